// Round 18
// baseline (63.882 us; speedup 1.0000x reference)
//
#include <hip/hip_runtime.h>

// Bahdanau attention. query [8][400][256], y [8][400][256], Wq_w [128][256],
// Wq_b [128], Wy_w [128][256], Wy_b [128], v_w [1][128], v_b (dropped:
// softmax shift-invariant), n_wins_y [8] i32. out [8][400][256] f32.
//
// score = sum_a v_a*tanh(qp+yp) ~ const + sum_a (-2 v_a)/(Eq_a*Ey_a + 1),
// Eq = e^{2 qp}, Ey = e^{2 yp} precomputed (1 fma/elem + 1 rcp/4).
//
// Lesson stack:
//  R4:  no runtime-indexed register arrays (scratch spill).
//  R7:  no lane-scattered global reads (W transposed in K0).
//  R10: broadcast loads scalarize ONLY if workgroup-uniform.
//  R11/R12: register-lean inner loops starve VGPRs & serialize latency.
//  R15: global loads must be LANE-UNIQUE (8-way-dup 128B loads = 8x VMEM).
//  R17: wave-owns-row apply works; but 400 blocks on 256 CUs = 1.56/CU
//       imbalance -> half the CUs idle. R18: apply split by d-half ->
//       (b,qg8,dh) = 800 balanced blocks; wave handles 2 rows/iter
//       (lane>>5 = row parity, lane&31 = d4 within half); y traffic
//       unchanged (160MB); per-wave VALU halves.

#define LOG2E 1.4426950408889634f
#define TANH_SCALE 2.8853900817779268f  // 2*log2(e)

constexpr int TQn = 400, TYn = 400, AD = 128, DD = 256;
constexpr int PTS = 12;  // pT row stride in floats (48B: 16B-aligned, b128-readable)

// ---------------- K0: WT4[k4][a] = W[a][4k4..4k4+3]; vneg = -2v ------------
__global__ __launch_bounds__(128) void transpose_kernel(
    const float* __restrict__ Wq, const float* __restrict__ Wy,
    const float* __restrict__ vw,
    float4* __restrict__ WTq, float4* __restrict__ WTy,
    float* __restrict__ vneg)
{
    const int k4 = blockIdx.x & 63;
    const bool isq = blockIdx.x < 64;
    const float4* src = reinterpret_cast<const float4*>(isq ? Wq : Wy);
    float4* dst = isq ? WTq : WTy;
    const int a = threadIdx.x;                 // 0..127
    dst[k4 * 128 + a] = src[a * 64 + k4];
    if (blockIdx.x == 0) vneg[a] = -2.f * vw[a];
}

// ---------------- K1: proj -> EqS packed / EyT transposed (R14-proven) -----
__global__ __launch_bounds__(256, 4) void proj_kernel(
    const float* __restrict__ qin, const float* __restrict__ yin,
    const float4* __restrict__ WTq, const float* __restrict__ bq,
    const float4* __restrict__ WTy, const float* __restrict__ by,
    float* __restrict__ EqS, float* __restrict__ EyT)
{
    const int blk = blockIdx.x;               // [0,800) q, [800,1600) y
    const bool is_q = blk < 800;
    const int row0 = (is_q ? blk : blk - 800) * 4;   // global row (b folded)
    const float* in   = (is_q ? qin : yin) + (size_t)row0 * DD;
    const float4* wt  = is_q ? WTq : WTy;     // [64 k4][128 a]
    const float* bias = is_q ? bq : by;

    __shared__ float lin[4 * DD];             // 4 KB
    __shared__ float red[4][AD];              // 2 KB
    {
        const float4* in4 = reinterpret_cast<const float4*>(in);
        reinterpret_cast<float4*>(lin)[threadIdx.x] = in4[threadIdx.x];  // 1/thread
    }
    __syncthreads();

    const int a = threadIdx.x & 127;
    const int h = threadIdx.x >> 7;           // k-half
    float acc[4] = {0.f, 0.f, 0.f, 0.f};
    const float4* l4 = reinterpret_cast<const float4*>(lin);
    #pragma unroll 8
    for (int i = 0; i < 32; ++i) {
        const int k4 = h * 32 + i;
        float4 w4 = wt[k4 * 128 + a];         // coalesced 16B/lane
        #pragma unroll
        for (int r = 0; r < 4; ++r) {
            float4 v = l4[r * 64 + k4];       // LDS broadcast (wave-uniform)
            acc[r] = fmaf(w4.x, v.x, acc[r]);
            acc[r] = fmaf(w4.y, v.y, acc[r]);
            acc[r] = fmaf(w4.z, v.z, acc[r]);
            acc[r] = fmaf(w4.w, v.w, acc[r]);
        }
    }
    if (h) {
        #pragma unroll
        for (int r = 0; r < 4; ++r) red[r][a] = acc[r];
    }
    __syncthreads();
    if (!h) {
        const float bb = bias[a];
        const int a4 = a >> 2, ac = a & 3;
        const int qoff = (row0 & 7);          // 0 or 4 within the 8q group
        #pragma unroll
        for (int r = 0; r < 4; ++r) {
            const float e = __builtin_amdgcn_exp2f(
                (acc[r] + red[r][a] + bb) * TANH_SCALE);
            if (is_q)
                EqS[(size_t)(row0 >> 3) * 1024 + a4 * 32 + (qoff + r) * 4 + ac] = e;
            else
                EyT[(size_t)a4 * 12800 + (size_t)(row0 + r) * 4 + ac] = e;
        }
    }
}

// ---------------- K2: raw scores (R14-proven); zero LDS/barriers; 4q -------
__global__ __launch_bounds__(448, 2) void score_kernel(
    const float* __restrict__ EqS,   // [400 qgrp][32][8][4]
    const float4* __restrict__ EyT4, // [32][3200]
    const float* __restrict__ vneg,  // [128] = -2v
    const int*  __restrict__ nwins,  // [B]
    float* __restrict__ s)           // [B][TQ][TY]
{
    const int grp = blockIdx.x;               // b*100 + qg
    const int b   = grp / 100;
    const int qg  = grp % 100;
    const int q0  = qg * 4;
    const int n   = nwins[b];
    const int t   = threadIdx.x;              // 0..447
    if ((t & ~63) >= n) return;               // wave-uniform early exit

    const int ycol = b * TYn + min(t, TYn - 1);
    const float4* eqg = reinterpret_cast<const float4*>(EqS)
                      + (size_t)(b * 50 + (qg >> 1)) * 256 + 4 * (qg & 1);
    const float4* vn4 = reinterpret_cast<const float4*>(vneg);

    float ac0 = 0.f, ac1 = 0.f, ac2 = 0.f, ac3 = 0.f;
    for (int a4 = 0; a4 < 32; ++a4) {
        const float4 ey = EyT4[(size_t)a4 * 3200 + ycol];  // coalesced 1KB
        const float4* eqa = eqg + a4 * 8;                  // uniform -> s_load
        const float4 vv = vn4[a4];                         // uniform -> s_load
        const float4 e0 = eqa[0], e1 = eqa[1], e2 = eqa[2], e3 = eqa[3];
        #define SCORE_Q(ACC, EQ)                                            \
        {                                                                   \
            float a0 = fmaf(EQ.x, ey.x, 1.f);                               \
            float a1 = fmaf(EQ.y, ey.y, 1.f);                               \
            float a2 = fmaf(EQ.z, ey.z, 1.f);                               \
            float a3 = fmaf(EQ.w, ey.w, 1.f);                               \
            float p01 = a0 * a1, p23 = a2 * a3;                             \
            float R = __builtin_amdgcn_rcpf(p01 * p23);                     \
            float u = p23 * R, w = p01 * R;                                 \
            ACC = fmaf(vv.x, a1 * u, ACC);                                  \
            ACC = fmaf(vv.y, a0 * u, ACC);                                  \
            ACC = fmaf(vv.z, a3 * w, ACC);                                  \
            ACC = fmaf(vv.w, a2 * w, ACC);                                  \
        }
        SCORE_Q(ac0, e0) SCORE_Q(ac1, e1) SCORE_Q(ac2, e2) SCORE_Q(ac3, e3)
        #undef SCORE_Q
    }
    if (t < n) {
        float* srow = s + (size_t)(b * TQn + q0) * TYn + t;
        srow[0 * TYn] = ac0; srow[1 * TYn] = ac1;
        srow[2 * TYn] = ac2; srow[3 * TYn] = ac3;
    }
}

// ---------------- K3: softmax + att@y; (b,qg8,dh) wave-owns-row-pair -------
__global__ __launch_bounds__(512, 4) void apply_kernel(
    const float* __restrict__ y,    // [B][TY][DD]
    const float* __restrict__ s,    // [B][TQ][TY]
    const int*  __restrict__ nwins, // [B]
    float* __restrict__ out)        // [B][TQ][DD]
{
    const int bid = blockIdx.x;               // 8 b x 50 qg x 2 dh = 800
    const int b   = bid / 100;
    const int rem = bid % 100;
    const int qg  = rem >> 1;
    const int dh  = rem & 1;
    const int q0  = qg * 8;
    const int tid = threadIdx.x, wave = tid >> 6, lane = tid & 63;
    const int n = nwins[b];
    const float NEG_INF = -__builtin_inff();

    // 19.2 KB: pT[400][PTS] floats; aliased as rbuf[8][2][64] f4 in reduce
    __shared__ __align__(16) float4 s_buf4[1200];
    float* s_pT = reinterpret_cast<float*>(s_buf4);

    // ---- softmax for q = q0 + wave (8 waves; duplicated across dh) ----
    const float* srow = s + (size_t)(b * TQn + q0 + wave) * TYn;
    float sc0, sc1, sc2, sc3, sc4, sc5, sc6;
    {
        int t;
        t = 0 * 64 + lane; sc0 = (t < n) ? srow[t] : NEG_INF;
        t = 1 * 64 + lane; sc1 = (t < n) ? srow[t] : NEG_INF;
        t = 2 * 64 + lane; sc2 = (t < n) ? srow[t] : NEG_INF;
        t = 3 * 64 + lane; sc3 = (t < n) ? srow[t] : NEG_INF;
        t = 4 * 64 + lane; sc4 = (t < n) ? srow[t] : NEG_INF;
        t = 5 * 64 + lane; sc5 = (t < n) ? srow[t] : NEG_INF;
        t = 6 * 64 + lane; sc6 = (t < n) ? srow[t] : NEG_INF;
    }
    float m = fmaxf(fmaxf(fmaxf(sc0, sc1), fmaxf(sc2, sc3)),
                    fmaxf(fmaxf(sc4, sc5), sc6));
    #pragma unroll
    for (int off = 32; off >= 1; off >>= 1) m = fmaxf(m, __shfl_xor(m, off, 64));
    sc0 = __builtin_amdgcn_exp2f((sc0 - m) * LOG2E);
    sc1 = __builtin_amdgcn_exp2f((sc1 - m) * LOG2E);
    sc2 = __builtin_amdgcn_exp2f((sc2 - m) * LOG2E);
    sc3 = __builtin_amdgcn_exp2f((sc3 - m) * LOG2E);
    sc4 = __builtin_amdgcn_exp2f((sc4 - m) * LOG2E);
    sc5 = __builtin_amdgcn_exp2f((sc5 - m) * LOG2E);
    sc6 = __builtin_amdgcn_exp2f((sc6 - m) * LOG2E);
    float l = ((sc0 + sc1) + (sc2 + sc3)) + ((sc4 + sc5) + sc6);
    #pragma unroll
    for (int off = 32; off >= 1; off >>= 1) l += __shfl_xor(l, off, 64);
    const float inv = 1.0f / l;
    // publish transposed: pT[t][wave]; zeros beyond n (exp2(-inf)=0)
    s_pT[(0 * 64 + lane) * PTS + wave] = sc0 * inv;
    s_pT[(1 * 64 + lane) * PTS + wave] = sc1 * inv;
    s_pT[(2 * 64 + lane) * PTS + wave] = sc2 * inv;
    s_pT[(3 * 64 + lane) * PTS + wave] = sc3 * inv;
    s_pT[(4 * 64 + lane) * PTS + wave] = sc4 * inv;
    s_pT[(5 * 64 + lane) * PTS + wave] = sc5 * inv;
    {
        const int t = 6 * 64 + lane;          // 384..447
        if (t < TYn) s_pT[t * PTS + wave] = sc6 * inv;
    }
    __syncthreads();                          // pT visible to all waves

    // ---- apply: wave w, iter i -> rows {16i+2w, 16i+2w+1};
    //      lane: row parity = lane>>5, d4 col = dh*32 + (lane&31) ----
    const int col = dh * 32 + (lane & 31);
    const int rp  = lane >> 5;                // row parity within pair
    const float4* yb4 = reinterpret_cast<const float4*>(y) + (size_t)(b * TYn) * 64;
    float4 ac0 = {0,0,0,0}, ac1 = {0,0,0,0}, ac2 = {0,0,0,0}, ac3 = {0,0,0,0};
    float4 ac4 = {0,0,0,0}, ac5 = {0,0,0,0}, ac6 = {0,0,0,0}, ac7 = {0,0,0,0};

    int r = 2 * wave + rp;                    // this lane's row, iter 0
    float4 yv = yb4[(size_t)r * 64 + col];
    float4 pa = *reinterpret_cast<const float4*>(&s_pT[r * PTS]);
    float4 pb = *reinterpret_cast<const float4*>(&s_pT[r * PTS + 4]);

    for (int i = 0; i < 25; ++i) {
        const float4 yc = yv, pac = pa, pbc = pb;
        if (i < 24) {                          // prefetch next row (r+16)
            const int rn = r + 16;
            yv = yb4[(size_t)rn * 64 + col];
            pa = *reinterpret_cast<const float4*>(&s_pT[rn * PTS]);
            pb = *reinterpret_cast<const float4*>(&s_pT[rn * PTS + 4]);
            r = rn;
        }
        ac0.x = fmaf(pac.x, yc.x, ac0.x); ac0.y = fmaf(pac.x, yc.y, ac0.y);
        ac0.z = fmaf(pac.x, yc.z, ac0.z); ac0.w = fmaf(pac.x, yc.w, ac0.w);
        ac1.x = fmaf(pac.y, yc.x, ac1.x); ac1.y = fmaf(pac.y, yc.y, ac1.y);
        ac1.z = fmaf(pac.y, yc.z, ac1.z); ac1.w = fmaf(pac.y, yc.w, ac1.w);
        ac2.x = fmaf(pac.z, yc.x, ac2.x); ac2.y = fmaf(pac.z, yc.y, ac2.y);
        ac2.z = fmaf(pac.z, yc.z, ac2.z); ac2.w = fmaf(pac.z, yc.w, ac2.w);
        ac3.x = fmaf(pac.w, yc.x, ac3.x); ac3.y = fmaf(pac.w, yc.y, ac3.y);
        ac3.z = fmaf(pac.w, yc.z, ac3.z); ac3.w = fmaf(pac.w, yc.w, ac3.w);
        ac4.x = fmaf(pbc.x, yc.x, ac4.x); ac4.y = fmaf(pbc.x, yc.y, ac4.y);
        ac4.z = fmaf(pbc.x, yc.z, ac4.z); ac4.w = fmaf(pbc.x, yc.w, ac4.w);
        ac5.x = fmaf(pbc.y, yc.x, ac5.x); ac5.y = fmaf(pbc.y, yc.y, ac5.y);
        ac5.z = fmaf(pbc.y, yc.z, ac5.z); ac5.w = fmaf(pbc.y, yc.w, ac5.w);
        ac6.x = fmaf(pbc.z, yc.x, ac6.x); ac6.y = fmaf(pbc.z, yc.y, ac6.y);
        ac6.z = fmaf(pbc.z, yc.z, ac6.z); ac6.w = fmaf(pbc.z, yc.w, ac6.w);
        ac7.x = fmaf(pbc.w, yc.x, ac7.x); ac7.y = fmaf(pbc.w, yc.y, ac7.y);
        ac7.z = fmaf(pbc.w, yc.z, ac7.z); ac7.w = fmaf(pbc.w, yc.w, ac7.w);
    }

    // ---- cross-wave + cross-parity reduce: 4 phases x (2 q) ----
    float4* rbuf = s_buf4;                    // [8 w][2 qi][64 lane]
    float4* o4 = reinterpret_cast<float4*>(out)
               + (size_t)(b * TQn + q0) * 64 + dh * 32;
    auto rphase = [&](float4 AQ, float4 BQ, int PH) {
        __syncthreads();  // prior phase reads (or pT reads) done
        rbuf[wave * 128 + lane]      = AQ;
        rbuf[wave * 128 + 64 + lane] = BQ;
        __syncthreads();
        if (tid < 64) {
            const int qi = tid >> 5, dr = tid & 31;
            float4 s0 = {0.f, 0.f, 0.f, 0.f};
            #pragma unroll
            for (int w2 = 0; w2 < 8; ++w2) {
                float4 va = rbuf[w2 * 128 + qi * 64 + dr];        // parity 0
                float4 vb = rbuf[w2 * 128 + qi * 64 + 32 + dr];   // parity 1
                s0.x += va.x + vb.x; s0.y += va.y + vb.y;
                s0.z += va.z + vb.z; s0.w += va.w + vb.w;
            }
            o4[(size_t)(PH * 2 + qi) * 64 + dr] = s0;
        }
    };
    rphase(ac0, ac1, 0);
    rphase(ac2, ac3, 1);
    rphase(ac4, ac5, 2);
    rphase(ac6, ac7, 3);
}

extern "C" void kernel_launch(void* const* d_in, const int* in_sizes, int n_in,
                              void* d_out, int out_size, void* d_ws, size_t ws_size,
                              hipStream_t stream) {
    const float* query = (const float*)d_in[0];
    const float* y     = (const float*)d_in[1];
    const float* Wq_w  = (const float*)d_in[2];
    const float* Wq_b  = (const float*)d_in[3];
    const float* Wy_w  = (const float*)d_in[4];
    const float* Wy_b  = (const float*)d_in[5];
    const float* v_w   = (const float*)d_in[6];
    // d_in[7] = v_b: softmax-invariant, dropped.
    const int* nw      = (const int*)d_in[8];
    float* out = (float*)d_out;

    float4* WTq  = (float4*)d_ws;                    // 131 KB
    float4* WTy  = WTq + 64 * 128;                   // 131 KB
    float*  vneg = (float*)(WTy + 64 * 128);         // 512 B (pad 1 KB)
    float*  EqS  = vneg + 256;                       // [400][32][8][4] = 1.64 MB
    float*  EyT  = EqS + (size_t)400 * 1024;         // [32][3200][4]  = 1.64 MB
    float*  s    = EyT + (size_t)32 * 3200 * 4;      // [8][400][400]  = 5.12 MB

    transpose_kernel<<<128, 128, 0, stream>>>(Wq_w, Wy_w, v_w, WTq, WTy, vneg);
    proj_kernel<<<1600, 256, 0, stream>>>(query, y, WTq, Wq_b, WTy, Wy_b, EqS, EyT);
    score_kernel<<<8 * 100, 448, 0, stream>>>(
        EqS, (const float4*)EyT, vneg, nw, s);
    apply_kernel<<<8 * 100, 512, 0, stream>>>(y, s, nw, out);
}

// Round 19
// 61.672 us; speedup vs baseline: 1.0358x; 1.0358x over previous
//
#include <hip/hip_runtime.h>

// Bahdanau attention. query [8][400][256], y [8][400][256], Wq_w [128][256],
// Wq_b [128], Wy_w [128][256], Wy_b [128], v_w [1][128], v_b (dropped:
// softmax shift-invariant), n_wins_y [8] i32. out [8][400][256] f32.
//
// score = sum_a v_a*tanh(qp+yp) ~ const + sum_a (-2 v_a)/(Eq_a*Ey_a + 1),
// Eq = e^{2 qp}, Ey = e^{2 yp} precomputed. Tree-combine: v0/a0+v1/a1 =
// (v0*a1+v1*a0)/(a0*a1) -> 14 VALU + 1 rcp per 4 elems per q.
//
// Lesson stack:
//  R4:  no runtime-indexed register arrays.  R7: no lane-scattered reads.
//  R10: broadcasts scalarize only if workgroup-uniform.
//  R11/R12: register-lean loops starve VGPRs.  R15: loads must be lane-unique.
//  R17: wave-owns-row apply. R18: don't duplicate softmax across split blocks.
//  R19: fuse score+softmax+apply (one kernel, 800 blocks (b,qg4) x 448):
//       no s round-trip, dynamic block scheduling smooths CU imbalance,
//       5.5 waves/SIMD through the whole fused body.

#define LOG2E 1.4426950408889634f
#define TANH_SCALE 2.8853900817779268f  // 2*log2(e)

constexpr int TQn = 400, TYn = 400, AD = 128, DD = 256;

// ---------------- K0: WT4[k4][a] = W[a][4k4..4k4+3]; vneg = -2v ------------
__global__ __launch_bounds__(128) void transpose_kernel(
    const float* __restrict__ Wq, const float* __restrict__ Wy,
    const float* __restrict__ vw,
    float4* __restrict__ WTq, float4* __restrict__ WTy,
    float* __restrict__ vneg)
{
    const int k4 = blockIdx.x & 63;
    const bool isq = blockIdx.x < 64;
    const float4* src = reinterpret_cast<const float4*>(isq ? Wq : Wy);
    float4* dst = isq ? WTq : WTy;
    const int a = threadIdx.x;                 // 0..127
    dst[k4 * 128 + a] = src[a * 64 + k4];
    if (blockIdx.x == 0) vneg[a] = -2.f * vw[a];
}

// ---------------- K1: proj -> EqS packed / EyT transposed (R14-proven) -----
__global__ __launch_bounds__(256, 4) void proj_kernel(
    const float* __restrict__ qin, const float* __restrict__ yin,
    const float4* __restrict__ WTq, const float* __restrict__ bq,
    const float4* __restrict__ WTy, const float* __restrict__ by,
    float* __restrict__ EqS, float* __restrict__ EyT)
{
    const int blk = blockIdx.x;               // [0,800) q, [800,1600) y
    const bool is_q = blk < 800;
    const int row0 = (is_q ? blk : blk - 800) * 4;   // global row (b folded)
    const float* in   = (is_q ? qin : yin) + (size_t)row0 * DD;
    const float4* wt  = is_q ? WTq : WTy;     // [64 k4][128 a]
    const float* bias = is_q ? bq : by;

    __shared__ float lin[4 * DD];             // 4 KB
    __shared__ float red[4][AD];              // 2 KB
    {
        const float4* in4 = reinterpret_cast<const float4*>(in);
        reinterpret_cast<float4*>(lin)[threadIdx.x] = in4[threadIdx.x];  // 1/thread
    }
    __syncthreads();

    const int a = threadIdx.x & 127;
    const int h = threadIdx.x >> 7;           // k-half
    float acc[4] = {0.f, 0.f, 0.f, 0.f};
    const float4* l4 = reinterpret_cast<const float4*>(lin);
    #pragma unroll 8
    for (int i = 0; i < 32; ++i) {
        const int k4 = h * 32 + i;
        float4 w4 = wt[k4 * 128 + a];         // coalesced 16B/lane
        #pragma unroll
        for (int r = 0; r < 4; ++r) {
            float4 v = l4[r * 64 + k4];       // LDS broadcast
            acc[r] = fmaf(w4.x, v.x, acc[r]);
            acc[r] = fmaf(w4.y, v.y, acc[r]);
            acc[r] = fmaf(w4.z, v.z, acc[r]);
            acc[r] = fmaf(w4.w, v.w, acc[r]);
        }
    }
    if (h) {
        #pragma unroll
        for (int r = 0; r < 4; ++r) red[r][a] = acc[r];
    }
    __syncthreads();
    if (!h) {
        const float bb = bias[a];
        const int a4 = a >> 2, ac = a & 3;
        const int qoff = (row0 & 7);          // 0 or 4 within the 8q group
        #pragma unroll
        for (int r = 0; r < 4; ++r) {
            const float e = __builtin_amdgcn_exp2f(
                (acc[r] + red[r][a] + bb) * TANH_SCALE);
            if (is_q)
                EqS[(size_t)(row0 >> 3) * 1024 + a4 * 32 + (qoff + r) * 4 + ac] = e;
            else
                EyT[(size_t)a4 * 12800 + (size_t)(row0 + r) * 4 + ac] = e;
        }
    }
}

// ---------------- K2: fused score -> softmax -> apply; (b, qg4) ------------
__global__ __launch_bounds__(448, 2) void fused_kernel(
    const float* __restrict__ EqS,   // [400 qgrp][32][8][4]
    const float4* __restrict__ EyT4, // [32][3200]
    const float* __restrict__ vneg,  // [128] = -2v
    const float* __restrict__ y,     // [B][TY][DD]
    const int*  __restrict__ nwins,  // [B]
    float* __restrict__ out)         // [B][TQ][DD]
{
    const int grp = blockIdx.x;               // b*100 + qg
    const int b   = grp / 100;
    const int qg  = grp % 100;
    const int q0  = qg * 4;
    const int n   = nwins[b];
    const int tid = threadIdx.x;              // 0..447
    const int wave = tid >> 6, lane = tid & 63;
    const float NEG_INF = -__builtin_inff();

    __shared__ __align__(16) float4 s_pT[448];       // 7 KB: p[t][4q]
    __shared__ __align__(16) float4 s_rbuf[7 * 128]; // 14.3 KB reduce buf
    __shared__ float s_wred[2][7][4];                // max/sum partials

    // ---- score: t = tid; 4 q via uniform s_loads; tree-combined rcp ----
    const int ycol = b * TYn + min(tid, TYn - 1);
    const float4* eqg = reinterpret_cast<const float4*>(EqS)
                      + (size_t)(b * 50 + (qg >> 1)) * 256 + 4 * (qg & 1);
    const float4* vn4 = reinterpret_cast<const float4*>(vneg);

    float ac0 = 0.f, ac1 = 0.f, ac2 = 0.f, ac3 = 0.f;
    for (int a4 = 0; a4 < 32; ++a4) {
        const float4 ey = EyT4[(size_t)a4 * 3200 + ycol];  // coalesced 1KB
        const float4* eqa = eqg + a4 * 8;                  // uniform -> s_load
        const float4 vv = vn4[a4];                         // uniform -> s_load
        const float4 e0 = eqa[0], e1 = eqa[1], e2 = eqa[2], e3 = eqa[3];
        #define SCORE_Q(ACC, EQ)                                            \
        {                                                                   \
            float a0 = fmaf(EQ.x, ey.x, 1.f);                               \
            float a1 = fmaf(EQ.y, ey.y, 1.f);                               \
            float a2 = fmaf(EQ.z, ey.z, 1.f);                               \
            float a3 = fmaf(EQ.w, ey.w, 1.f);                               \
            float n01 = fmaf(vv.x, a1, vv.y * a0);                          \
            float n23 = fmaf(vv.z, a3, vv.w * a2);                          \
            float d01 = a0 * a1, d23 = a2 * a3;                             \
            float N = fmaf(n01, d23, n23 * d01);                            \
            float R = __builtin_amdgcn_rcpf(d01 * d23);                     \
            ACC = fmaf(N, R, ACC);                                          \
        }
        SCORE_Q(ac0, e0) SCORE_Q(ac1, e1) SCORE_Q(ac2, e2) SCORE_Q(ac3, e3)
        #undef SCORE_Q
    }
    if (tid >= n) { ac0 = NEG_INF; ac1 = NEG_INF; ac2 = NEG_INF; ac3 = NEG_INF; }

    // ---- softmax over t (cross-wave via LDS partials) ----
    float m0 = ac0, m1 = ac1, m2 = ac2, m3 = ac3;
    #pragma unroll
    for (int off = 32; off >= 1; off >>= 1) {
        m0 = fmaxf(m0, __shfl_xor(m0, off, 64));
        m1 = fmaxf(m1, __shfl_xor(m1, off, 64));
        m2 = fmaxf(m2, __shfl_xor(m2, off, 64));
        m3 = fmaxf(m3, __shfl_xor(m3, off, 64));
    }
    if (lane == 0) {
        s_wred[0][wave][0] = m0; s_wred[0][wave][1] = m1;
        s_wred[0][wave][2] = m2; s_wred[0][wave][3] = m3;
    }
    __syncthreads();
    m0 = s_wred[0][0][0]; m1 = s_wred[0][0][1];
    m2 = s_wred[0][0][2]; m3 = s_wred[0][0][3];
    #pragma unroll
    for (int w2 = 1; w2 < 7; ++w2) {
        m0 = fmaxf(m0, s_wred[0][w2][0]); m1 = fmaxf(m1, s_wred[0][w2][1]);
        m2 = fmaxf(m2, s_wred[0][w2][2]); m3 = fmaxf(m3, s_wred[0][w2][3]);
    }
    float p0 = __builtin_amdgcn_exp2f((ac0 - m0) * LOG2E);  // 0 for masked
    float p1 = __builtin_amdgcn_exp2f((ac1 - m1) * LOG2E);
    float p2 = __builtin_amdgcn_exp2f((ac2 - m2) * LOG2E);
    float p3 = __builtin_amdgcn_exp2f((ac3 - m3) * LOG2E);
    float l0 = p0, l1 = p1, l2 = p2, l3 = p3;
    #pragma unroll
    for (int off = 32; off >= 1; off >>= 1) {
        l0 += __shfl_xor(l0, off, 64);
        l1 += __shfl_xor(l1, off, 64);
        l2 += __shfl_xor(l2, off, 64);
        l3 += __shfl_xor(l3, off, 64);
    }
    if (lane == 0) {
        s_wred[1][wave][0] = l0; s_wred[1][wave][1] = l1;
        s_wred[1][wave][2] = l2; s_wred[1][wave][3] = l3;
    }
    __syncthreads();
    l0 = s_wred[1][0][0]; l1 = s_wred[1][0][1];
    l2 = s_wred[1][0][2]; l3 = s_wred[1][0][3];
    #pragma unroll
    for (int w2 = 1; w2 < 7; ++w2) {
        l0 += s_wred[1][w2][0]; l1 += s_wred[1][w2][1];
        l2 += s_wred[1][w2][2]; l3 += s_wred[1][w2][3];
    }
    float4 pv;
    pv.x = p0 * (1.0f / l0);
    pv.y = p1 * (1.0f / l1);
    pv.z = p2 * (1.0f / l2);
    pv.w = p3 * (1.0f / l3);
    s_pT[tid] = pv;                           // p[t][4q]; zeros beyond n
    __syncthreads();

    // ---- apply: wave owns rows rr = wave + 7*i; lane = d4 (1KB coalesced) ----
    const float4* yb4 = reinterpret_cast<const float4*>(y) + (size_t)(b * TYn) * 64;
    float4 A0 = {0,0,0,0}, A1 = {0,0,0,0}, A2 = {0,0,0,0}, A3 = {0,0,0,0};

    int rA = wave;                            // depth-2 named pipeline
    float4 yA = yb4[(size_t)min(rA, TYn - 1) * 64 + lane];
    float4 pA = s_pT[rA];
    int rB = wave + 7;
    float4 yB = yb4[(size_t)min(rB, TYn - 1) * 64 + lane];
    float4 pB = s_pT[rB];

    for (int i = 0; i < 29; ++i) {            // 58 rows: wave+7*57 <= 405 < 448
        {
            const float4 yc = yA, pc = pA;
            if (i < 28) {
                const int rn = rA + 14;
                yA = yb4[(size_t)min(rn, TYn - 1) * 64 + lane];
                pA = s_pT[rn];
                rA = rn;
            }
            A0.x = fmaf(pc.x, yc.x, A0.x); A0.y = fmaf(pc.x, yc.y, A0.y);
            A0.z = fmaf(pc.x, yc.z, A0.z); A0.w = fmaf(pc.x, yc.w, A0.w);
            A1.x = fmaf(pc.y, yc.x, A1.x); A1.y = fmaf(pc.y, yc.y, A1.y);
            A1.z = fmaf(pc.y, yc.z, A1.z); A1.w = fmaf(pc.y, yc.w, A1.w);
            A2.x = fmaf(pc.z, yc.x, A2.x); A2.y = fmaf(pc.z, yc.y, A2.y);
            A2.z = fmaf(pc.z, yc.z, A2.z); A2.w = fmaf(pc.z, yc.w, A2.w);
            A3.x = fmaf(pc.w, yc.x, A3.x); A3.y = fmaf(pc.w, yc.y, A3.y);
            A3.z = fmaf(pc.w, yc.z, A3.z); A3.w = fmaf(pc.w, yc.w, A3.w);
        }
        {
            const float4 yc = yB, pc = pB;
            if (i < 28) {
                const int rn = rB + 14;
                yB = yb4[(size_t)min(rn, TYn - 1) * 64 + lane];
                pB = s_pT[rn];
                rB = rn;
            }
            A0.x = fmaf(pc.x, yc.x, A0.x); A0.y = fmaf(pc.x, yc.y, A0.y);
            A0.z = fmaf(pc.x, yc.z, A0.z); A0.w = fmaf(pc.x, yc.w, A0.w);
            A1.x = fmaf(pc.y, yc.x, A1.x); A1.y = fmaf(pc.y, yc.y, A1.y);
            A1.z = fmaf(pc.y, yc.z, A1.z); A1.w = fmaf(pc.y, yc.w, A1.w);
            A2.x = fmaf(pc.z, yc.x, A2.x); A2.y = fmaf(pc.z, yc.y, A2.y);
            A2.z = fmaf(pc.z, yc.z, A2.z); A2.w = fmaf(pc.z, yc.w, A2.w);
            A3.x = fmaf(pc.w, yc.x, A3.x); A3.y = fmaf(pc.w, yc.y, A3.y);
            A3.z = fmaf(pc.w, yc.z, A3.z); A3.w = fmaf(pc.w, yc.w, A3.w);
        }
    }

    // ---- cross-wave reduce: 2 phases x 2 q ----
    float4* o4 = reinterpret_cast<float4*>(out) + (size_t)(b * TQn + q0) * 64;
    auto rphase = [&](float4 AQ, float4 BQ, int PH) {
        __syncthreads();  // prior phase reads done (pT reads done pre-phase-0)
        s_rbuf[wave * 128 + lane]      = AQ;
        s_rbuf[wave * 128 + 64 + lane] = BQ;
        __syncthreads();
        if (tid < 128) {
            const int qi = tid >> 6, dr = tid & 63;
            float4 s0 = s_rbuf[qi * 64 + dr];
            #pragma unroll
            for (int w2 = 1; w2 < 7; ++w2) {
                float4 v = s_rbuf[w2 * 128 + qi * 64 + dr];
                s0.x += v.x; s0.y += v.y; s0.z += v.z; s0.w += v.w;
            }
            o4[(size_t)(PH * 2 + qi) * 64 + dr] = s0;
        }
    };
    rphase(A0, A1, 0);
    rphase(A2, A3, 1);
}

extern "C" void kernel_launch(void* const* d_in, const int* in_sizes, int n_in,
                              void* d_out, int out_size, void* d_ws, size_t ws_size,
                              hipStream_t stream) {
    const float* query = (const float*)d_in[0];
    const float* y     = (const float*)d_in[1];
    const float* Wq_w  = (const float*)d_in[2];
    const float* Wq_b  = (const float*)d_in[3];
    const float* Wy_w  = (const float*)d_in[4];
    const float* Wy_b  = (const float*)d_in[5];
    const float* v_w   = (const float*)d_in[6];
    // d_in[7] = v_b: softmax-invariant, dropped.
    const int* nw      = (const int*)d_in[8];
    float* out = (float*)d_out;

    float4* WTq  = (float4*)d_ws;                    // 131 KB
    float4* WTy  = WTq + 64 * 128;                   // 131 KB
    float*  vneg = (float*)(WTy + 64 * 128);         // 512 B (pad 1 KB)
    float*  EqS  = vneg + 256;                       // [400][32][8][4] = 1.64 MB
    float*  EyT  = EqS + (size_t)400 * 1024;         // [32][3200][4]  = 1.64 MB

    transpose_kernel<<<128, 128, 0, stream>>>(Wq_w, Wy_w, v_w, WTq, WTy, vneg);
    proj_kernel<<<1600, 256, 0, stream>>>(query, y, WTq, Wq_b, WTy, Wy_b, EqS, EyT);
    fused_kernel<<<8 * 100, 448, 0, stream>>>(
        EqS, (const float4*)EyT, vneg, y, nw, out);
}